// Round 1
// baseline (2275.325 us; speedup 1.0000x reference)
//
#include <hip/hip_runtime.h>

#define DD 512
#define TT 16384
#define CC 8192
#define EPS_DIV 1e-6f
#define EPS_NORM 1e-12f
#define EPS_PD 1e-6f

// ---------------- GEMM: imp = codebook @ W^T  [CC x DD] ----------------
// 64x64 tile, BK=16, 256 threads, 4x4 micro-tile.
__global__ __launch_bounds__(256) void k_gemm_imp(
    const float* __restrict__ cb, const float* __restrict__ W,
    float* __restrict__ imp) {
  __shared__ float As[16][68];
  __shared__ float Bs[16][68];
  const int tid = threadIdx.x;
  const int tx = tid & 15, ty = tid >> 4;
  const int c0 = blockIdx.x * 64;
  const int d0 = blockIdx.y * 64;
  const int lr = tid >> 2;          // 0..63: tile row this thread stages
  const int lk = (tid & 3) << 2;    // 0,4,8,12: k offset
  float acc[4][4] = {};
  for (int k0 = 0; k0 < DD; k0 += 16) {
    float4 av = *(const float4*)(cb + (size_t)(c0 + lr) * DD + k0 + lk);
    float4 bv = *(const float4*)(W  + (size_t)(d0 + lr) * DD + k0 + lk);
    __syncthreads();
    As[lk + 0][lr] = av.x; As[lk + 1][lr] = av.y;
    As[lk + 2][lr] = av.z; As[lk + 3][lr] = av.w;
    Bs[lk + 0][lr] = bv.x; Bs[lk + 1][lr] = bv.y;
    Bs[lk + 2][lr] = bv.z; Bs[lk + 3][lr] = bv.w;
    __syncthreads();
#pragma unroll
    for (int k = 0; k < 16; ++k) {
      float4 a = *(const float4*)&As[k][ty << 2];
      float4 b = *(const float4*)&Bs[k][tx << 2];
      float ar[4] = {a.x, a.y, a.z, a.w};
      float br[4] = {b.x, b.y, b.z, b.w};
#pragma unroll
      for (int i = 0; i < 4; ++i)
#pragma unroll
        for (int j = 0; j < 4; ++j) acc[i][j] = fmaf(ar[i], br[j], acc[i][j]);
    }
  }
#pragma unroll
  for (int i = 0; i < 4; ++i) {
    float4 o = make_float4(acc[i][0], acc[i][1], acc[i][2], acc[i][3]);
    *(float4*)(imp + (size_t)(c0 + (ty << 2) + i) * DD + d0 + (tx << 2)) = o;
  }
}

// ---------------- per-code squared norms ----------------
// one wave per code row; block = 4 waves.
__global__ __launch_bounds__(256) void k_row_norm2(
    const float* __restrict__ imp, float* __restrict__ cnorm) {
  const int lane = threadIdx.x & 63;
  const int row = blockIdx.x * 4 + (threadIdx.x >> 6);
  const float* p = imp + (size_t)row * DD + lane * 8;
  float4 a = *(const float4*)p;
  float4 b = *(const float4*)(p + 4);
  float s = a.x * a.x + a.y * a.y + a.z * a.z + a.w * a.w +
            b.x * b.x + b.y * b.y + b.z * b.z + b.w * b.w;
#pragma unroll
  for (int m = 1; m < 64; m <<= 1) s += __shfl_xor(s, m);
  if (lane == 0) cnorm[row] = s;
}

// ---------------- fused distance GEMM + argmin ----------------
// grid (TT/64, 2): 64 x-rows per block, each block scans half the codebook.
// score(c) = ||imp_c||^2 - 2 * x . imp_c   (||x||^2 dropped: row-constant)
__global__ __launch_bounds__(256) void k_dist_argmin(
    const float* __restrict__ x, const float* __restrict__ imp,
    const float* __restrict__ cnorm,
    float* __restrict__ bval, int* __restrict__ bidx) {
  __shared__ float As[16][68];
  __shared__ float Bs[16][68];
  __shared__ float rv[64][17];
  __shared__ int   ri[64][17];
  const int tid = threadIdx.x;
  const int tx = tid & 15, ty = tid >> 4;
  const int r0 = blockIdx.x * 64;
  const int cbase = blockIdx.y * (CC / 2);
  const int lr = tid >> 2;
  const int lk = (tid & 3) << 2;
  float bestv[4] = {3.4e38f, 3.4e38f, 3.4e38f, 3.4e38f};
  int besti[4] = {0, 0, 0, 0};

  for (int ct = 0; ct < CC / 2; ct += 64) {
    float acc[4][4] = {};
    for (int k0 = 0; k0 < DD; k0 += 16) {
      float4 av = *(const float4*)(x   + (size_t)(r0 + lr) * DD + k0 + lk);
      float4 bv = *(const float4*)(imp + (size_t)(cbase + ct + lr) * DD + k0 + lk);
      __syncthreads();
      As[lk + 0][lr] = av.x; As[lk + 1][lr] = av.y;
      As[lk + 2][lr] = av.z; As[lk + 3][lr] = av.w;
      Bs[lk + 0][lr] = bv.x; Bs[lk + 1][lr] = bv.y;
      Bs[lk + 2][lr] = bv.z; Bs[lk + 3][lr] = bv.w;
      __syncthreads();
#pragma unroll
      for (int k = 0; k < 16; ++k) {
        float4 a = *(const float4*)&As[k][ty << 2];
        float4 b = *(const float4*)&Bs[k][tx << 2];
        float ar[4] = {a.x, a.y, a.z, a.w};
        float br[4] = {b.x, b.y, b.z, b.w};
#pragma unroll
        for (int i = 0; i < 4; ++i)
#pragma unroll
          for (int j = 0; j < 4; ++j) acc[i][j] = fmaf(ar[i], br[j], acc[i][j]);
      }
    }
    // fold this c-tile into per-thread running best (c scanned in increasing
    // order; strict < keeps the lowest index on exact ties)
#pragma unroll
    for (int j = 0; j < 4; ++j) {
      const int c = cbase + ct + (tx << 2) + j;
      const float nn = cnorm[c];
#pragma unroll
      for (int i = 0; i < 4; ++i) {
        float v = fmaf(-2.0f, acc[i][j], nn);
        if (v < bestv[i]) { bestv[i] = v; besti[i] = c; }
      }
    }
  }
  // cross-thread (tx) reduction per tile row
#pragma unroll
  for (int i = 0; i < 4; ++i) {
    rv[(ty << 2) + i][tx] = bestv[i];
    ri[(ty << 2) + i][tx] = besti[i];
  }
  __syncthreads();
  if (tid < 64) {
    float v = rv[tid][0];
    int ix = ri[tid][0];
#pragma unroll
    for (int t = 1; t < 16; ++t) {
      float v2 = rv[tid][t];
      int i2 = ri[tid][t];
      if (v2 < v || (v2 == v && i2 < ix)) { v = v2; ix = i2; }
    }
    bval[blockIdx.y * TT + r0 + tid] = v;
    bidx[blockIdx.y * TT + r0 + tid] = ix;
  }
}

// ---------------- epilogue: merge halves, gather, rotation trick ----------------
// one wave per x-row; block = 4 waves.
__global__ __launch_bounds__(256) void k_epilogue(
    const float* __restrict__ x, const float* __restrict__ imp,
    const float* __restrict__ bval, const int* __restrict__ bidx,
    float* __restrict__ outq, float* __restrict__ outidx,
    float* __restrict__ rloss) {
  const int lane = threadIdx.x & 63;
  const int row = blockIdx.x * 4 + (threadIdx.x >> 6);
  const float v0 = bval[row], v1 = bval[TT + row];
  const int i0 = bidx[row], i1 = bidx[TT + row];
  const int idx = (v1 < v0) ? i1 : i0;  // tie -> lower half -> lower index

  const float* xr = x + (size_t)row * DD + lane * 8;
  const float* qr = imp + (size_t)idx * DD + lane * 8;
  float e[8], q[8];
  *(float4*)&e[0] = *(const float4*)xr;
  *(float4*)&e[4] = *(const float4*)(xr + 4);
  *(float4*)&q[0] = *(const float4*)qr;
  *(float4*)&q[4] = *(const float4*)(qr + 4);

  float xx = 0.f, qq = 0.f, xq = 0.f, cl = 0.f;
#pragma unroll
  for (int k = 0; k < 8; ++k) {
    xx = fmaf(e[k], e[k], xx);
    qq = fmaf(q[k], q[k], qq);
    xq = fmaf(e[k], q[k], xq);
    float d = e[k] - q[k] + EPS_PD;
    cl = fmaf(d, d, cl);
  }
#pragma unroll
  for (int m = 1; m < 64; m <<= 1) {
    xx += __shfl_xor(xx, m);
    qq += __shfl_xor(qq, m);
    xq += __shfl_xor(xq, m);
    cl += __shfl_xor(cl, m);
  }
  const float nx = sqrtf(xx), nq = sqrtf(qq);
  const float dx = fmaxf(nx, EPS_DIV), dq = fmaxf(nq, EPS_DIV);
  const float uu = xx / (dx * dx);
  const float qq2 = qq / (dq * dq);
  const float uq = xq / (dx * dq);
  const float ss = uu + qq2 + 2.0f * uq;       // ||u + q'||^2
  const float dn = fmaxf(sqrtf(ss), EPS_NORM); // clamp(||s||)
  const float es = xx / dx + xq / dq;          // e.u + e.q'
  const float a = 2.0f * es / (dn * dn);
  const float b = 2.0f * (xx / dx);            // 2 (e.u)
  const float scale = nq / dx;                 // norm_q / max(norm_x, eps)

  float o[8];
#pragma unroll
  for (int k = 0; k < 8; ++k) {
    const float qp = q[k] / dq;                // q'_k
    const float sk = e[k] / dx + qp;           // s_k
    o[k] = (e[k] - a * sk + b * qp) * scale;
  }
  float* op = outq + (size_t)row * DD + lane * 8;
  *(float4*)op = *(const float4*)&o[0];
  *(float4*)(op + 4) = *(const float4*)&o[4];
  if (lane == 0) {
    outidx[row] = (float)idx;
    rloss[row] = cl;
  }
}

// ---------------- final loss reduction (deterministic) ----------------
__global__ __launch_bounds__(256) void k_loss_final(
    const float* __restrict__ rloss, float* __restrict__ out) {
  __shared__ double red[256];
  const int tid = threadIdx.x;
  double s = 0.0;
  for (int i = tid; i < TT; i += 256) s += (double)rloss[i];
  red[tid] = s;
  __syncthreads();
  for (int st = 128; st > 0; st >>= 1) {
    if (tid < st) red[tid] += red[tid + st];
    __syncthreads();
  }
  if (tid == 0) out[0] = (float)(red[0] / (double)TT);
}

extern "C" void kernel_launch(void* const* d_in, const int* in_sizes, int n_in,
                              void* d_out, int out_size, void* d_ws, size_t ws_size,
                              hipStream_t stream) {
  const float* x  = (const float*)d_in[0];   // [TT, DD]
  const float* W  = (const float*)d_in[1];   // [DD, DD]
  const float* cb = (const float*)d_in[2];   // [CC, DD]
  float* out = (float*)d_out;

  // workspace layout (floats)
  float* imp   = (float*)d_ws;               // CC*DD        = 4194304
  float* bval  = imp + (size_t)CC * DD;      // 2*TT         = 32768
  int*   bidx  = (int*)(bval + 2 * TT);      // 2*TT         = 32768
  float* cnorm = (float*)(bidx + 2 * TT);    // CC           = 8192
  float* rloss = cnorm + CC;                 // TT           = 16384

  float* out_q    = out;                     // TT*DD
  float* out_idx  = out + (size_t)TT * DD;   // TT
  float* out_loss = out_idx + TT;            // 1

  k_gemm_imp<<<dim3(CC / 64, DD / 64), 256, 0, stream>>>(cb, W, imp);
  k_row_norm2<<<CC / 4, 256, 0, stream>>>(imp, cnorm);
  k_dist_argmin<<<dim3(TT / 64, 2), 256, 0, stream>>>(x, imp, cnorm, bval, bidx);
  k_epilogue<<<TT / 4, 256, 0, stream>>>(x, imp, bval, bidx, out_q, out_idx, rloss);
  k_loss_final<<<1, 256, 0, stream>>>(rloss, out_loss);
}

// Round 2
// 737.880 us; speedup vs baseline: 3.0836x; 3.0836x over previous
//
#include <hip/hip_runtime.h>
#include <cstdint>
#include <cstddef>

#define DD 512
#define TT 16384
#define CC 8192
#define SPLITC 8
#define EPS_DIV 1e-6f
#define EPS_NORM 1e-12f
#define EPS_PD 1e-6f

typedef _Float16 half8 __attribute__((ext_vector_type(8)));
typedef _Float16 half4 __attribute__((ext_vector_type(4)));
typedef float floatx4 __attribute__((ext_vector_type(4)));

// async global->LDS, 16B per lane; lds base must be wave-uniform
#define GLDS16(g, l) __builtin_amdgcn_global_load_lds( \
    (const __attribute__((address_space(1))) void*)(g), \
    (__attribute__((address_space(3))) void*)(l), 16, 0, 0)

// ---------------- GEMM: imp = codebook @ W^T  [CC x DD], exact fp32 ----------------
__global__ __launch_bounds__(256) void k_gemm_imp(
    const float* __restrict__ cb, const float* __restrict__ W,
    float* __restrict__ imp) {
  __shared__ float As[16][68];
  __shared__ float Bs[16][68];
  const int tid = threadIdx.x;
  const int tx = tid & 15, ty = tid >> 4;
  const int c0 = blockIdx.x * 64;
  const int d0 = blockIdx.y * 64;
  const int lr = tid >> 2;
  const int lk = (tid & 3) << 2;
  float acc[4][4] = {};
  for (int k0 = 0; k0 < DD; k0 += 16) {
    float4 av = *(const float4*)(cb + (size_t)(c0 + lr) * DD + k0 + lk);
    float4 bv = *(const float4*)(W  + (size_t)(d0 + lr) * DD + k0 + lk);
    __syncthreads();
    As[lk + 0][lr] = av.x; As[lk + 1][lr] = av.y;
    As[lk + 2][lr] = av.z; As[lk + 3][lr] = av.w;
    Bs[lk + 0][lr] = bv.x; Bs[lk + 1][lr] = bv.y;
    Bs[lk + 2][lr] = bv.z; Bs[lk + 3][lr] = bv.w;
    __syncthreads();
#pragma unroll
    for (int k = 0; k < 16; ++k) {
      float4 a = *(const float4*)&As[k][ty << 2];
      float4 b = *(const float4*)&Bs[k][tx << 2];
      float ar[4] = {a.x, a.y, a.z, a.w};
      float br[4] = {b.x, b.y, b.z, b.w};
#pragma unroll
      for (int i = 0; i < 4; ++i)
#pragma unroll
        for (int j = 0; j < 4; ++j) acc[i][j] = fmaf(ar[i], br[j], acc[i][j]);
    }
  }
#pragma unroll
  for (int i = 0; i < 4; ++i) {
    float4 o = make_float4(acc[i][0], acc[i][1], acc[i][2], acc[i][3]);
    *(float4*)(imp + (size_t)(c0 + (ty << 2) + i) * DD + d0 + (tx << 2)) = o;
  }
}

// ---------------- per-code squared norms (fp32, exact) ----------------
__global__ __launch_bounds__(256) void k_row_norm2(
    const float* __restrict__ imp, float* __restrict__ cnorm) {
  const int lane = threadIdx.x & 63;
  const int row = blockIdx.x * 4 + (threadIdx.x >> 6);
  const float* p = imp + (size_t)row * DD + lane * 8;
  float4 a = *(const float4*)p;
  float4 b = *(const float4*)(p + 4);
  float s = a.x * a.x + a.y * a.y + a.z * a.z + a.w * a.w +
            b.x * b.x + b.y * b.y + b.z * b.z + b.w * b.w;
#pragma unroll
  for (int m = 1; m < 64; m <<= 1) s += __shfl_xor(s, m);
  if (lane == 0) cnorm[row] = s;
}

// ---------------- split fp32 -> (hi, lo) fp16, layout [row][0:512]=hi [512:1024]=lo ----------------
__global__ __launch_bounds__(128) void k_split(const float* __restrict__ src,
                                               _Float16* __restrict__ dst) {
  const int row = blockIdx.x;
  const int col = threadIdx.x * 4;
  float4 v = *(const float4*)(src + (size_t)row * DD + col);
  half4 h, l;
  h.x = (_Float16)v.x; l.x = (_Float16)(v.x - (float)h.x);
  h.y = (_Float16)v.y; l.y = (_Float16)(v.y - (float)h.y);
  h.z = (_Float16)v.z; l.z = (_Float16)(v.z - (float)h.z);
  h.w = (_Float16)v.w; l.w = (_Float16)(v.w - (float)h.w);
  *(half4*)(dst + (size_t)row * 1024 + col) = h;
  *(half4*)(dst + (size_t)row * 1024 + 512 + col) = l;
}

// ---------------- fused split-fp16 MFMA distance + argmin ----------------
// 128x128 tile (rows=x, cols=codes), 4 waves in 2x2, 16x16x32 f16 MFMA, BK=32.
// score(c) = ||imp_c||^2 - 2 * x.imp_c ; dot = hi.hi + hi.lo + lo.hi (3 passes).
__global__ __launch_bounds__(256) void k_dist_mfma(
    const _Float16* __restrict__ xh, const _Float16* __restrict__ ih,
    const float* __restrict__ cnorm,
    float* __restrict__ bval, int* __restrict__ bidx) {
  __shared__ __align__(16) char smem[33792];  // tiles (16KB) / reduction (33KB) overlap
  _Float16* Al = (_Float16*)smem;             // [128][32] halfs, 8KB
  _Float16* Bl = (_Float16*)(smem + 8192);    // [128][32] halfs, 8KB
  const int tid = threadIdx.x;
  const int w = tid >> 6, lane = tid & 63;
  const int quad = lane >> 4, l15 = lane & 15;
  const int wm = (w & 1) * 64, wn = (w >> 1) * 64;
  const int r0 = blockIdx.x * 128;
  const int cbase = blockIdx.y * (CC / SPLITC);
  // staging: lane -> (row = w*16 + lane/4, col8 = (lane&3)*8), 16B per lane
  const int srow = w * 16 + (lane >> 2);
  const int scol = (lane & 3) * 8;
  const size_t sOff = (size_t)srow * 1024 + scol;
  const _Float16* xb = xh + (size_t)r0 * 1024 + sOff;
  _Float16* Alp0 = Al + w * 512;
  _Float16* Alp1 = Al + 2048 + w * 512;
  _Float16* Blp0 = Bl + w * 512;
  _Float16* Blp1 = Bl + 2048 + w * 512;
  const int AOFF[3] = {0, 0, 512};
  const int BOFF[3] = {0, 512, 0};

  float best[16];
  int bsti[16];
#pragma unroll
  for (int i = 0; i < 16; ++i) { best[i] = 3.4e38f; bsti[i] = 0; }

  for (int ct = 0; ct < CC / SPLITC / 128; ++ct) {
    const _Float16* ib = ih + (size_t)(cbase + ct * 128) * 1024 + sOff;
    floatx4 acc[4][4] = {};
    for (int p = 0; p < 3; ++p) {
      const _Float16* ap = xb + AOFF[p];
      const _Float16* bp = ib + BOFF[p];
      for (int k0 = 0; k0 < 512; k0 += 32) {
        __syncthreads();
        GLDS16(ap + k0, Alp0);
        GLDS16(ap + k0 + 64 * 1024, Alp1);
        GLDS16(bp + k0, Blp0);
        GLDS16(bp + k0 + 64 * 1024, Blp1);
        __syncthreads();
        half8 a[4], b[4];
#pragma unroll
        for (int mi = 0; mi < 4; ++mi)
          a[mi] = *(const half8*)&Al[(wm + mi * 16 + l15) * 32 + quad * 8];
#pragma unroll
        for (int ni = 0; ni < 4; ++ni)
          b[ni] = *(const half8*)&Bl[(wn + ni * 16 + l15) * 32 + quad * 8];
#pragma unroll
        for (int mi = 0; mi < 4; ++mi)
#pragma unroll
          for (int ni = 0; ni < 4; ++ni)
            acc[mi][ni] = __builtin_amdgcn_mfma_f32_16x16x32_f16(
                a[mi], b[ni], acc[mi][ni], 0, 0, 0);
      }
    }
    // fold c-tile into per-thread running best; c increases with (ct, ni) so
    // strict < keeps the lowest index on exact ties
#pragma unroll
    for (int ni = 0; ni < 4; ++ni) {
      const int c = cbase + ct * 128 + wn + ni * 16 + l15;
      const float nn = cnorm[c];
#pragma unroll
      for (int mi = 0; mi < 4; ++mi)
#pragma unroll
        for (int r = 0; r < 4; ++r) {
          const float v = fmaf(-2.0f, acc[mi][ni][r], nn);
          const int s = mi * 4 + r;
          if (v < best[s]) { best[s] = v; bsti[s] = c; }
        }
    }
  }
  // cross-lane/wave reduction: row m held by 2 waves x 16 lanes (one quad each)
  __syncthreads();
  float* rv = (float*)smem;            // [128][33]
  int* ri = (int*)(smem + 16896);      // [128][33]
  const int e = (w >> 1) * 16 + l15;   // 0..31
#pragma unroll
  for (int mi = 0; mi < 4; ++mi)
#pragma unroll
    for (int r = 0; r < 4; ++r) {
      const int row = wm + mi * 16 + quad * 4 + r;
      rv[row * 33 + e] = best[mi * 4 + r];
      ri[row * 33 + e] = bsti[mi * 4 + r];
    }
  __syncthreads();
  if (tid < 128) {
    float v = rv[tid * 33];
    int ix = ri[tid * 33];
#pragma unroll
    for (int t = 1; t < 32; ++t) {
      const float v2 = rv[tid * 33 + t];
      const int i2 = ri[tid * 33 + t];
      if (v2 < v || (v2 == v && i2 < ix)) { v = v2; ix = i2; }
    }
    bval[blockIdx.y * TT + r0 + tid] = v;
    bidx[blockIdx.y * TT + r0 + tid] = ix;
  }
}

// ---------------- epilogue: merge partials, gather, rotation trick ----------------
__global__ __launch_bounds__(256) void k_epilogue(
    const float* __restrict__ x, const float* __restrict__ imp,
    const float* __restrict__ bval, const int* __restrict__ bidx,
    float* __restrict__ outq, float* __restrict__ outidx,
    float* __restrict__ rloss) {
  const int lane = threadIdx.x & 63;
  const int row = blockIdx.x * 4 + (threadIdx.x >> 6);
  float v = bval[row];
  int ix = bidx[row];
#pragma unroll
  for (int p = 1; p < SPLITC; ++p) {
    const float v2 = bval[p * TT + row];
    const int i2 = bidx[p * TT + row];
    if (v2 < v || (v2 == v && i2 < ix)) { v = v2; ix = i2; }
  }
  const int idx = ix;

  const float* xr = x + (size_t)row * DD + lane * 8;
  const float* qr = imp + (size_t)idx * DD + lane * 8;
  float e[8], q[8];
  *(float4*)&e[0] = *(const float4*)xr;
  *(float4*)&e[4] = *(const float4*)(xr + 4);
  *(float4*)&q[0] = *(const float4*)qr;
  *(float4*)&q[4] = *(const float4*)(qr + 4);

  float xx = 0.f, qq = 0.f, xq = 0.f, cl = 0.f;
#pragma unroll
  for (int k = 0; k < 8; ++k) {
    xx = fmaf(e[k], e[k], xx);
    qq = fmaf(q[k], q[k], qq);
    xq = fmaf(e[k], q[k], xq);
    float d = e[k] - q[k] + EPS_PD;
    cl = fmaf(d, d, cl);
  }
#pragma unroll
  for (int m = 1; m < 64; m <<= 1) {
    xx += __shfl_xor(xx, m);
    qq += __shfl_xor(qq, m);
    xq += __shfl_xor(xq, m);
    cl += __shfl_xor(cl, m);
  }
  const float nx = sqrtf(xx), nq = sqrtf(qq);
  const float dx = fmaxf(nx, EPS_DIV), dq = fmaxf(nq, EPS_DIV);
  const float uu = xx / (dx * dx);
  const float qq2 = qq / (dq * dq);
  const float uq = xq / (dx * dq);
  const float ss = uu + qq2 + 2.0f * uq;
  const float dn = fmaxf(sqrtf(ss), EPS_NORM);
  const float es = xx / dx + xq / dq;
  const float a = 2.0f * es / (dn * dn);
  const float b = 2.0f * (xx / dx);
  const float scale = nq / dx;

  float o[8];
#pragma unroll
  for (int k = 0; k < 8; ++k) {
    const float qp = q[k] / dq;
    const float sk = e[k] / dx + qp;
    o[k] = (e[k] - a * sk + b * qp) * scale;
  }
  float* op = outq + (size_t)row * DD + lane * 8;
  *(float4*)op = *(const float4*)&o[0];
  *(float4*)(op + 4) = *(const float4*)&o[4];
  if (lane == 0) {
    outidx[row] = (float)idx;
    rloss[row] = cl;
  }
}

// ---------------- final loss reduction (deterministic) ----------------
__global__ __launch_bounds__(256) void k_loss_final(
    const float* __restrict__ rloss, float* __restrict__ out) {
  __shared__ double red[256];
  const int tid = threadIdx.x;
  double s = 0.0;
  for (int i = tid; i < TT; i += 256) s += (double)rloss[i];
  red[tid] = s;
  __syncthreads();
  for (int st = 128; st > 0; st >>= 1) {
    if (tid < st) red[tid] += red[tid + st];
    __syncthreads();
  }
  if (tid == 0) out[0] = (float)(red[0] / (double)TT);
}

extern "C" void kernel_launch(void* const* d_in, const int* in_sizes, int n_in,
                              void* d_out, int out_size, void* d_ws, size_t ws_size,
                              hipStream_t stream) {
  const float* x  = (const float*)d_in[0];   // [TT, DD]
  const float* W  = (const float*)d_in[1];   // [DD, DD]
  const float* cb = (const float*)d_in[2];   // [CC, DD]
  float* out = (float*)d_out;

  // workspace layout (~65 MiB)
  float* imp = (float*)d_ws;                            // CC*DD fp32
  _Float16* xh = (_Float16*)(imp + (size_t)CC * DD);    // TT*1024 halfs (32 MiB)
  _Float16* ih = xh + (size_t)TT * 1024;                // CC*1024 halfs (16 MiB)
  float* cnorm = (float*)(ih + (size_t)CC * 1024);      // CC
  float* bval  = cnorm + CC;                            // SPLITC*TT
  int*   bidx  = (int*)(bval + (size_t)SPLITC * TT);    // SPLITC*TT
  float* rloss = (float*)(bidx + (size_t)SPLITC * TT);  // TT

  float* out_q    = out;
  float* out_idx  = out + (size_t)TT * DD;
  float* out_loss = out_idx + TT;

  k_gemm_imp<<<dim3(CC / 64, DD / 64), 256, 0, stream>>>(cb, W, imp);
  k_row_norm2<<<CC / 4, 256, 0, stream>>>(imp, cnorm);
  k_split<<<CC, 128, 0, stream>>>(imp, ih);
  k_split<<<TT, 128, 0, stream>>>(x, xh);
  k_dist_mfma<<<dim3(TT / 128, SPLITC), 256, 0, stream>>>(xh, ih, cnorm, bval, bidx);
  k_epilogue<<<TT / 4, 256, 0, stream>>>(x, imp, bval, bidx, out_q, out_idx, rloss);
  k_loss_final<<<1, 256, 0, stream>>>(rloss, out_loss);
}

// Round 3
// 399.097 us; speedup vs baseline: 5.7012x; 1.8489x over previous
//
#include <hip/hip_runtime.h>
#include <cstdint>
#include <cstddef>

#define DD 512
#define TT 16384
#define CC 8192
#define SPLITC 16
#define EPS_DIV 1e-6f
#define EPS_NORM 1e-12f
#define EPS_PD 1e-6f

typedef _Float16 half8 __attribute__((ext_vector_type(8)));
typedef _Float16 half4 __attribute__((ext_vector_type(4)));
typedef float floatx4 __attribute__((ext_vector_type(4)));

// async global->LDS, 16B per lane; lds base must be wave-uniform
#define GLDS16(g, l) __builtin_amdgcn_global_load_lds( \
    (const __attribute__((address_space(1))) void*)(g), \
    (__attribute__((address_space(3))) void*)(l), 16, 0, 0)

// ---------------- GEMM: imp = codebook @ W^T  [CC x DD], exact fp32 ----------------
__global__ __launch_bounds__(256) void k_gemm_imp(
    const float* __restrict__ cb, const float* __restrict__ W,
    float* __restrict__ imp) {
  __shared__ float As[16][68];
  __shared__ float Bs[16][68];
  const int tid = threadIdx.x;
  const int tx = tid & 15, ty = tid >> 4;
  const int c0 = blockIdx.x * 64;
  const int d0 = blockIdx.y * 64;
  const int lr = tid >> 2;
  const int lk = (tid & 3) << 2;
  float acc[4][4] = {};
  for (int k0 = 0; k0 < DD; k0 += 16) {
    float4 av = *(const float4*)(cb + (size_t)(c0 + lr) * DD + k0 + lk);
    float4 bv = *(const float4*)(W  + (size_t)(d0 + lr) * DD + k0 + lk);
    __syncthreads();
    As[lk + 0][lr] = av.x; As[lk + 1][lr] = av.y;
    As[lk + 2][lr] = av.z; As[lk + 3][lr] = av.w;
    Bs[lk + 0][lr] = bv.x; Bs[lk + 1][lr] = bv.y;
    Bs[lk + 2][lr] = bv.z; Bs[lk + 3][lr] = bv.w;
    __syncthreads();
#pragma unroll
    for (int k = 0; k < 16; ++k) {
      float4 a = *(const float4*)&As[k][ty << 2];
      float4 b = *(const float4*)&Bs[k][tx << 2];
      float ar[4] = {a.x, a.y, a.z, a.w};
      float br[4] = {b.x, b.y, b.z, b.w};
#pragma unroll
      for (int i = 0; i < 4; ++i)
#pragma unroll
        for (int j = 0; j < 4; ++j) acc[i][j] = fmaf(ar[i], br[j], acc[i][j]);
    }
  }
#pragma unroll
  for (int i = 0; i < 4; ++i) {
    float4 o = make_float4(acc[i][0], acc[i][1], acc[i][2], acc[i][3]);
    *(float4*)(imp + (size_t)(c0 + (ty << 2) + i) * DD + d0 + (tx << 2)) = o;
  }
}

// ---------------- per-code squared norms (fp32) ----------------
__global__ __launch_bounds__(256) void k_row_norm2(
    const float* __restrict__ imp, float* __restrict__ cnorm) {
  const int lane = threadIdx.x & 63;
  const int row = blockIdx.x * 4 + (threadIdx.x >> 6);
  const float* p = imp + (size_t)row * DD + lane * 8;
  float4 a = *(const float4*)p;
  float4 b = *(const float4*)(p + 4);
  float s = a.x * a.x + a.y * a.y + a.z * a.z + a.w * a.w +
            b.x * b.x + b.y * b.y + b.z * b.z + b.w * b.w;
#pragma unroll
  for (int m = 1; m < 64; m <<= 1) s += __shfl_xor(s, m);
  if (lane == 0) cnorm[row] = s;
}

// ---------------- cast fp32 -> fp16 (hi only), [row][512] ----------------
__global__ __launch_bounds__(128) void k_cast16(const float* __restrict__ src,
                                                _Float16* __restrict__ dst) {
  const int row = blockIdx.x;
  const int col = threadIdx.x * 4;
  float4 v = *(const float4*)(src + (size_t)row * DD + col);
  half4 h;
  h.x = (_Float16)v.x; h.y = (_Float16)v.y;
  h.z = (_Float16)v.z; h.w = (_Float16)v.w;
  *(half4*)(dst + (size_t)row * DD + col) = h;
}

// ---------------- phase 1: fp16 hi.hi MFMA scores + per-row TOP-2 ----------------
// 128x128 tile, 4 waves 2x2, 16x16x32 f16, BK=64 (32 MFMA per barrier pair).
// LDS col-block XOR swizzle (lane&7)^(lane>>3) keeps frag reads conflict-free
// while satisfying global_load_lds's lane-ordered deposit.
// score(c) = ||imp_c||^2 - 2 * xh . ih_c   (approx; exact rescore in epilogue)
__global__ __launch_bounds__(256) void k_dist_top2(
    const _Float16* __restrict__ xh, const _Float16* __restrict__ ih,
    const float* __restrict__ cnorm,
    float* __restrict__ bval, int* __restrict__ bidx) {
  __shared__ __align__(16) char smem[33792];  // tiles 32KB / top2-reduce 33KB overlap
  _Float16* Al = (_Float16*)smem;             // [128][64] halfs, 16KB
  _Float16* Bl = (_Float16*)(smem + 16384);   // [128][64] halfs, 16KB
  const int tid = threadIdx.x;
  const int w = tid >> 6, lane = tid & 63;
  const int quad = lane >> 4, l15 = lane & 15;
  const int wm = (w & 1) * 64, wn = (w >> 1) * 64;
  const int r0 = blockIdx.x * 128;
  const int cbase = blockIdx.y * (CC / SPLITC);

  // staging map: lane -> (local row = lane>>3, phys col-block = lane&7),
  // which holds logical col-block (lane&7)^(lane>>3)  [XOR swizzle]
  const int srow8 = lane >> 3;
  const int scol = ((lane & 7) ^ srow8) << 3;   // halfs
  // per-issue j: rows j*32 + w*8 .. +8
  size_t arow[4], brow[4];
#pragma unroll
  for (int j = 0; j < 4; ++j) {
    arow[j] = (size_t)(r0 + j * 32 + w * 8 + srow8) * DD + scol;
    brow[j] = (size_t)(j * 32 + w * 8 + srow8) * DD + scol;
  }
  _Float16* aldst[4];
  _Float16* bldst[4];
#pragma unroll
  for (int j = 0; j < 4; ++j) {
    aldst[j] = Al + (j * 32 + w * 8) * 64;
    bldst[j] = Bl + (j * 32 + w * 8) * 64;
  }

  float best[16];
  int bsti[16];
#pragma unroll
  for (int i = 0; i < 16; ++i) { best[i] = 3.4e38f; bsti[i] = 0; }

  for (int ct = 0; ct < CC / SPLITC / 128; ++ct) {   // 4 c-tiles
    const _Float16* bsrc = ih + (size_t)(cbase + ct * 128) * DD;
    floatx4 acc[4][4] = {};
    for (int k0 = 0; k0 < DD; k0 += 64) {
      __syncthreads();
#pragma unroll
      for (int j = 0; j < 4; ++j) GLDS16(xh + arow[j] + k0, aldst[j]);
#pragma unroll
      for (int j = 0; j < 4; ++j) GLDS16(bsrc + brow[j] + k0, bldst[j]);
      __syncthreads();
#pragma unroll
      for (int ks = 0; ks < 64; ks += 32) {
        half8 a[4], b[4];
#pragma unroll
        for (int mi = 0; mi < 4; ++mi)
          a[mi] = *(const half8*)&Al[(wm + mi * 16 + l15) * 64 +
                                     ((((ks >> 3) + quad) ^ (l15 & 7)) << 3)];
#pragma unroll
        for (int ni = 0; ni < 4; ++ni)
          b[ni] = *(const half8*)&Bl[(wn + ni * 16 + l15) * 64 +
                                     ((((ks >> 3) + quad) ^ (l15 & 7)) << 3)];
#pragma unroll
        for (int mi = 0; mi < 4; ++mi)
#pragma unroll
          for (int ni = 0; ni < 4; ++ni)
            acc[mi][ni] = __builtin_amdgcn_mfma_f32_16x16x32_f16(
                a[mi], b[ni], acc[mi][ni], 0, 0, 0);
      }
    }
    // fold c-tile into per-slot running top-1 (c ascends; strict < keeps lowest idx)
#pragma unroll
    for (int ni = 0; ni < 4; ++ni) {
      const int c = cbase + ct * 128 + wn + ni * 16 + l15;
      const float nn = cnorm[c];
#pragma unroll
      for (int mi = 0; mi < 4; ++mi)
#pragma unroll
        for (int r = 0; r < 4; ++r) {
          const float v = fmaf(-2.0f, acc[mi][ni][r], nn);
          const int s = mi * 4 + r;
          if (v < best[s]) { best[s] = v; bsti[s] = c; }
        }
    }
  }
  // cross-entry reduction to per-row TOP-2 (32 entries per row)
  __syncthreads();
  float* rv = (float*)smem;            // [128][33]
  int* ri = (int*)(smem + 16896);      // [128][33]
  const int e = (w >> 1) * 16 + l15;   // 0..31
#pragma unroll
  for (int mi = 0; mi < 4; ++mi)
#pragma unroll
    for (int r = 0; r < 4; ++r) {
      const int row = wm + mi * 16 + quad * 4 + r;
      rv[row * 33 + e] = best[mi * 4 + r];
      ri[row * 33 + e] = bsti[mi * 4 + r];
    }
  __syncthreads();
  if (tid < 128) {
    float v1 = 3.4e38f, v2 = 3.4e38f;
    int i1 = 0x7fffffff, i2 = 0x7fffffff;
#pragma unroll
    for (int t = 0; t < 32; ++t) {
      const float v = rv[tid * 33 + t];
      const int i = ri[tid * 33 + t];
      if (v < v1 || (v == v1 && i < i1)) {
        v2 = v1; i2 = i1; v1 = v; i1 = i;
      } else if (v < v2 || (v == v2 && i < i2)) {
        v2 = v; i2 = i;
      }
    }
    const size_t o = ((size_t)blockIdx.y * TT + r0 + tid) * 2;
    bval[o] = v1; bval[o + 1] = v2;
    bidx[o] = i1; bidx[o + 1] = i2;
  }
}

// ---------------- epilogue: merge top-2, exact rescore, rotation trick ----------------
__global__ __launch_bounds__(256) void k_epilogue(
    const float* __restrict__ x, const float* __restrict__ imp,
    const float* __restrict__ cnorm,
    const float* __restrict__ bval, const int* __restrict__ bidx,
    float* __restrict__ outq, float* __restrict__ outidx,
    float* __restrict__ rloss) {
  const int lane = threadIdx.x & 63;
  const int row = blockIdx.x * 4 + (threadIdx.x >> 6);
  // merge SPLITC x 2 candidates -> global top-2 (approx order, index ties low)
  float v1 = 3.4e38f, v2 = 3.4e38f;
  int i1 = 0x7fffffff, i2 = 0x7fffffff;
#pragma unroll
  for (int p = 0; p < SPLITC; ++p) {
    const size_t o = ((size_t)p * TT + row) * 2;
#pragma unroll
    for (int h = 0; h < 2; ++h) {
      const float v = bval[o + h];
      const int i = bidx[o + h];
      if (v < v1 || (v == v1 && i < i1)) {
        v2 = v1; i2 = i1; v1 = v; i1 = i;
      } else if (v < v2 || (v == v2 && i < i2)) {
        v2 = v; i2 = i;
      }
    }
  }
  // exact fp32 rescore of both candidates
  const float* xr = x + (size_t)row * DD + lane * 8;
  float e[8], qa[8], qb[8];
  *(float4*)&e[0] = *(const float4*)xr;
  *(float4*)&e[4] = *(const float4*)(xr + 4);
  const float* q1p = imp + (size_t)i1 * DD + lane * 8;
  const float* q2p = imp + (size_t)i2 * DD + lane * 8;
  *(float4*)&qa[0] = *(const float4*)q1p;
  *(float4*)&qa[4] = *(const float4*)(q1p + 4);
  *(float4*)&qb[0] = *(const float4*)q2p;
  *(float4*)&qb[4] = *(const float4*)(q2p + 4);
  float d1 = 0.f, d2 = 0.f;
#pragma unroll
  for (int k = 0; k < 8; ++k) {
    d1 = fmaf(e[k], qa[k], d1);
    d2 = fmaf(e[k], qb[k], d2);
  }
#pragma unroll
  for (int m = 1; m < 64; m <<= 1) {
    d1 += __shfl_xor(d1, m);
    d2 += __shfl_xor(d2, m);
  }
  const float s1 = fmaf(-2.0f, d1, cnorm[i1]);
  const float s2 = fmaf(-2.0f, d2, cnorm[i2]);
  const bool use2 = (s2 < s1) || (s2 == s1 && i2 < i1);
  const int idx = use2 ? i2 : i1;
  float q[8];
#pragma unroll
  for (int k = 0; k < 8; ++k) q[k] = use2 ? qb[k] : qa[k];

  float xx = 0.f, qq = 0.f, xq = 0.f, cl = 0.f;
#pragma unroll
  for (int k = 0; k < 8; ++k) {
    xx = fmaf(e[k], e[k], xx);
    qq = fmaf(q[k], q[k], qq);
    xq = fmaf(e[k], q[k], xq);
    float d = e[k] - q[k] + EPS_PD;
    cl = fmaf(d, d, cl);
  }
#pragma unroll
  for (int m = 1; m < 64; m <<= 1) {
    xx += __shfl_xor(xx, m);
    qq += __shfl_xor(qq, m);
    xq += __shfl_xor(xq, m);
    cl += __shfl_xor(cl, m);
  }
  const float nx = sqrtf(xx), nq = sqrtf(qq);
  const float dx = fmaxf(nx, EPS_DIV), dq = fmaxf(nq, EPS_DIV);
  const float uu = xx / (dx * dx);
  const float qq2 = qq / (dq * dq);
  const float uq = xq / (dx * dq);
  const float ss = uu + qq2 + 2.0f * uq;
  const float dn = fmaxf(sqrtf(ss), EPS_NORM);
  const float es = xx / dx + xq / dq;
  const float a = 2.0f * es / (dn * dn);
  const float b = 2.0f * (xx / dx);
  const float scale = nq / dx;

  float o[8];
#pragma unroll
  for (int k = 0; k < 8; ++k) {
    const float qp = q[k] / dq;
    const float sk = e[k] / dx + qp;
    o[k] = (e[k] - a * sk + b * qp) * scale;
  }
  float* op = outq + (size_t)row * DD + lane * 8;
  *(float4*)op = *(const float4*)&o[0];
  *(float4*)(op + 4) = *(const float4*)&o[4];
  if (lane == 0) {
    outidx[row] = (float)idx;
    rloss[row] = cl;
  }
}

// ---------------- final loss reduction (deterministic) ----------------
__global__ __launch_bounds__(256) void k_loss_final(
    const float* __restrict__ rloss, float* __restrict__ out) {
  __shared__ double red[256];
  const int tid = threadIdx.x;
  double s = 0.0;
  for (int i = tid; i < TT; i += 256) s += (double)rloss[i];
  red[tid] = s;
  __syncthreads();
  for (int st = 128; st > 0; st >>= 1) {
    if (tid < st) red[tid] += red[tid + st];
    __syncthreads();
  }
  if (tid == 0) out[0] = (float)(red[0] / (double)TT);
}

extern "C" void kernel_launch(void* const* d_in, const int* in_sizes, int n_in,
                              void* d_out, int out_size, void* d_ws, size_t ws_size,
                              hipStream_t stream) {
  const float* x  = (const float*)d_in[0];   // [TT, DD]
  const float* W  = (const float*)d_in[1];   // [DD, DD]
  const float* cb = (const float*)d_in[2];   // [CC, DD]
  float* out = (float*)d_out;

  // workspace layout (~49 MiB)
  float* imp = (float*)d_ws;                            // CC*DD fp32 (16 MiB)
  _Float16* xh = (_Float16*)(imp + (size_t)CC * DD);    // TT*DD halfs (16 MiB)
  _Float16* ih = xh + (size_t)TT * DD;                  // CC*DD halfs (8 MiB)
  float* cnorm = (float*)(ih + (size_t)CC * DD);        // CC
  float* bval  = cnorm + CC;                            // SPLITC*TT*2 (2 MiB)
  int*   bidx  = (int*)(bval + (size_t)SPLITC * TT * 2);
  float* rloss = (float*)(bidx + (size_t)SPLITC * TT * 2);

  float* out_q    = out;
  float* out_idx  = out + (size_t)TT * DD;
  float* out_loss = out_idx + TT;

  k_gemm_imp<<<dim3(CC / 64, DD / 64), 256, 0, stream>>>(cb, W, imp);
  k_row_norm2<<<CC / 4, 256, 0, stream>>>(imp, cnorm);
  k_cast16<<<CC, 128, 0, stream>>>(imp, ih);
  k_cast16<<<TT, 128, 0, stream>>>(x, xh);
  k_dist_top2<<<dim3(TT / 128, SPLITC), 256, 0, stream>>>(xh, ih, cnorm, bval, bidx);
  k_epilogue<<<TT / 4, 256, 0, stream>>>(x, imp, cnorm, bval, bidx, out_q, out_idx, rloss);
  k_loss_final<<<1, 256, 0, stream>>>(rloss, out_loss);
}

// Round 4
// 353.497 us; speedup vs baseline: 6.4366x; 1.1290x over previous
//
#include <hip/hip_runtime.h>
#include <cstdint>
#include <cstddef>

#define DD 512
#define TT 16384
#define CC 8192
#define SPLITC 64
#define EPS_DIV 1e-6f
#define EPS_NORM 1e-12f
#define EPS_PD 1e-6f

typedef _Float16 half8 __attribute__((ext_vector_type(8)));
typedef _Float16 half4 __attribute__((ext_vector_type(4)));
typedef float floatx4 __attribute__((ext_vector_type(4)));

// async global->LDS, 16B per lane; lds base must be wave-uniform
#define GLDS16(g, l) __builtin_amdgcn_global_load_lds( \
    (const __attribute__((address_space(1))) void*)(g), \
    (__attribute__((address_space(3))) void*)(l), 16, 0, 0)

// ---------------- split fp32 -> (hi, lo) fp16, [row][0:512]=hi [512:1024]=lo ----------------
__global__ __launch_bounds__(128) void k_split(const float* __restrict__ src,
                                               _Float16* __restrict__ dst) {
  const int row = blockIdx.x;
  const int col = threadIdx.x * 4;
  float4 v = *(const float4*)(src + (size_t)row * DD + col);
  half4 h, l;
  h.x = (_Float16)v.x; l.x = (_Float16)(v.x - (float)h.x);
  h.y = (_Float16)v.y; l.y = (_Float16)(v.y - (float)h.y);
  h.z = (_Float16)v.z; l.z = (_Float16)(v.z - (float)h.z);
  h.w = (_Float16)v.w; l.w = (_Float16)(v.w - (float)h.w);
  *(half4*)(dst + (size_t)row * 1024 + col) = h;
  *(half4*)(dst + (size_t)row * 1024 + 512 + col) = l;
}

// ---------------- cast fp32 -> fp16 (hi only), [row][512] ----------------
__global__ __launch_bounds__(128) void k_cast16(const float* __restrict__ src,
                                                _Float16* __restrict__ dst) {
  const int row = blockIdx.x;
  const int col = threadIdx.x * 4;
  float4 v = *(const float4*)(src + (size_t)row * DD + col);
  half4 h;
  h.x = (_Float16)v.x; h.y = (_Float16)v.y;
  h.z = (_Float16)v.z; h.w = (_Float16)v.w;
  *(half4*)(dst + (size_t)row * DD + col) = h;
}

// ---------------- imp = cb @ W^T via split-fp16 3-pass MFMA ----------------
// A=cbs [CC][1024] (hi|lo), B=Ws [DD][1024]. imp = ch.wh + ch.wl + cl.wh.
// 128x128 tile, 4 waves 2x2, BK=64, double-buffered LDS, writes imp fp32 + ih fp16.
__global__ __launch_bounds__(256) void k_gemm_mfma(
    const _Float16* __restrict__ cbs, const _Float16* __restrict__ Ws,
    float* __restrict__ imp, _Float16* __restrict__ ih) {
  __shared__ __align__(16) char smem[65536];  // A0,B0,A1,B1 @ 16KB each
  const int tid = threadIdx.x;
  const int w = tid >> 6, lane = tid & 63;
  const int quad = lane >> 4, l15 = lane & 15;
  const int wm = (w & 1) * 64, wn = (w >> 1) * 64;
  const int c0 = blockIdx.x * 128;
  const int n0 = blockIdx.y * 128;

  const int srow8 = lane >> 3;
  const int scol = ((lane & 7) ^ srow8) << 3;  // halfs, XOR-swizzled col block
  size_t arow[4], brow[4];
#pragma unroll
  for (int j = 0; j < 4; ++j) {
    arow[j] = (size_t)(c0 + j * 32 + w * 8 + srow8) * 1024 + scol;
    brow[j] = (size_t)(n0 + j * 32 + w * 8 + srow8) * 1024 + scol;
  }
  int aoff[4], boff[4];
#pragma unroll
  for (int i = 0; i < 4; ++i) {
    aoff[i] = ((wm + i * 16 + l15) * 64 + ((quad ^ (l15 & 7)) << 3)) * 2;
    boff[i] = ((wn + i * 16 + l15) * 64 + ((quad ^ (l15 & 7)) << 3)) * 2;
  }

  auto stage = [&](int buf, int ak, int bk) {
    char* ab = smem + buf * 32768;
    char* bb = ab + 16384;
#pragma unroll
    for (int j = 0; j < 4; ++j) {
      GLDS16(cbs + arow[j] + ak, (_Float16*)ab + (j * 32 + w * 8) * 64);
      GLDS16(Ws  + brow[j] + bk, (_Float16*)bb + (j * 32 + w * 8) * 64);
    }
  };

  floatx4 acc[4][4] = {};
  stage(0, 0, 0);
#pragma unroll 2
  for (int it = 0; it < 24; ++it) {   // 3 passes x 8 k-steps
    __syncthreads();
    if (it < 23) {
      const int n = it + 1;
      const int p = n >> 3, kk = n & 7;
      const int ak = ((p == 2) ? 512 : 0) + kk * 64;
      const int bk = ((p == 1) ? 512 : 0) + kk * 64;
      stage(n & 1, ak, bk);
    }
    const char* ab = smem + (it & 1) * 32768;
    const char* bb = ab + 16384;
#pragma unroll
    for (int ks = 0; ks < 2; ++ks) {
      const int kx = ks * 64;  // byte XOR for col-block +4
      half8 a[4], b[4];
#pragma unroll
      for (int mi = 0; mi < 4; ++mi)
        a[mi] = *(const half8*)(ab + (aoff[mi] ^ kx));
#pragma unroll
      for (int ni = 0; ni < 4; ++ni)
        b[ni] = *(const half8*)(bb + (boff[ni] ^ kx));
#pragma unroll
      for (int mi = 0; mi < 4; ++mi)
#pragma unroll
        for (int ni = 0; ni < 4; ++ni)
          acc[mi][ni] = __builtin_amdgcn_mfma_f32_16x16x32_f16(
              a[mi], b[ni], acc[mi][ni], 0, 0, 0);
    }
  }
  // C/D layout: col=lane&15, row=quad*4+reg
#pragma unroll
  for (int mi = 0; mi < 4; ++mi)
#pragma unroll
    for (int r = 0; r < 4; ++r) {
      const int c = c0 + wm + mi * 16 + quad * 4 + r;
#pragma unroll
      for (int ni = 0; ni < 4; ++ni) {
        const int d = n0 + wn + ni * 16 + l15;
        const float v = acc[mi][ni][r];
        imp[(size_t)c * DD + d] = v;
        ih[(size_t)c * DD + d] = (_Float16)v;
      }
    }
}

// ---------------- per-code squared norms (fp32) ----------------
__global__ __launch_bounds__(256) void k_row_norm2(
    const float* __restrict__ imp, float* __restrict__ cnorm) {
  const int lane = threadIdx.x & 63;
  const int row = blockIdx.x * 4 + (threadIdx.x >> 6);
  const float* p = imp + (size_t)row * DD + lane * 8;
  float4 a = *(const float4*)p;
  float4 b = *(const float4*)(p + 4);
  float s = a.x * a.x + a.y * a.y + a.z * a.z + a.w * a.w +
            b.x * b.x + b.y * b.y + b.z * b.z + b.w * b.w;
#pragma unroll
  for (int m = 1; m < 64; m <<= 1) s += __shfl_xor(s, m);
  if (lane == 0) cnorm[row] = s;
}

// ---------------- phase 1: fp16 hi.hi MFMA scores + per-row TOP-2 ----------------
// One 128-row x 128-code tile per block, K=512 streamed with dbuf LDS,
// one barrier per k-step, hoisted XOR-swizzled frag addresses.
__global__ __launch_bounds__(256) void k_dist_top2(
    const _Float16* __restrict__ xh, const _Float16* __restrict__ ih,
    const float* __restrict__ cnorm,
    float* __restrict__ bval, int* __restrict__ bidx) {
  __shared__ __align__(16) char smem[65536];  // A0,B0,A1,B1 @16KB; reduce scratch overlaps
  const int tid = threadIdx.x;
  const int w = tid >> 6, lane = tid & 63;
  const int quad = lane >> 4, l15 = lane & 15;
  const int wm = (w & 1) * 64, wn = (w >> 1) * 64;
  const int r0 = blockIdx.x * 128;
  const int c0 = blockIdx.y * 128;

  const int srow8 = lane >> 3;
  const int scol = ((lane & 7) ^ srow8) << 3;
  size_t arow[4], brow[4];
#pragma unroll
  for (int j = 0; j < 4; ++j) {
    arow[j] = (size_t)(r0 + j * 32 + w * 8 + srow8) * DD + scol;
    brow[j] = (size_t)(c0 + j * 32 + w * 8 + srow8) * DD + scol;
  }
  int aoff[4], boff[4];
#pragma unroll
  for (int i = 0; i < 4; ++i) {
    aoff[i] = ((wm + i * 16 + l15) * 64 + ((quad ^ (l15 & 7)) << 3)) * 2;
    boff[i] = ((wn + i * 16 + l15) * 64 + ((quad ^ (l15 & 7)) << 3)) * 2;
  }

  auto stage = [&](int buf, int k0) {
    char* ab = smem + buf * 32768;
    char* bb = ab + 16384;
#pragma unroll
    for (int j = 0; j < 4; ++j) {
      GLDS16(xh + arow[j] + k0, (_Float16*)ab + (j * 32 + w * 8) * 64);
      GLDS16(ih + brow[j] + k0, (_Float16*)bb + (j * 32 + w * 8) * 64);
    }
  };

  floatx4 acc[4][4] = {};
  stage(0, 0);
#pragma unroll
  for (int kk = 0; kk < 8; ++kk) {
    __syncthreads();
    if (kk < 7) stage((kk + 1) & 1, (kk + 1) * 64);
    const char* ab = smem + (kk & 1) * 32768;
    const char* bb = ab + 16384;
#pragma unroll
    for (int ks = 0; ks < 2; ++ks) {
      const int kx = ks * 64;
      half8 a[4], b[4];
#pragma unroll
      for (int mi = 0; mi < 4; ++mi)
        a[mi] = *(const half8*)(ab + (aoff[mi] ^ kx));
#pragma unroll
      for (int ni = 0; ni < 4; ++ni)
        b[ni] = *(const half8*)(bb + (boff[ni] ^ kx));
#pragma unroll
      for (int mi = 0; mi < 4; ++mi)
#pragma unroll
        for (int ni = 0; ni < 4; ++ni)
          acc[mi][ni] = __builtin_amdgcn_mfma_f32_16x16x32_f16(
              a[mi], b[ni], acc[mi][ni], 0, 0, 0);
    }
  }
  // fold 4 ni-candidates per slot (c ascends with ni; strict < keeps lowest idx)
  float best[16];
  int bsti[16];
#pragma unroll
  for (int mi = 0; mi < 4; ++mi)
#pragma unroll
    for (int r = 0; r < 4; ++r) {
      const int s = mi * 4 + r;
      best[s] = 3.4e38f; bsti[s] = 0;
#pragma unroll
      for (int ni = 0; ni < 4; ++ni) {
        const int c = c0 + wn + ni * 16 + l15;
        const float v = fmaf(-2.0f, acc[mi][ni][r], cnorm[c]);
        if (v < best[s]) { best[s] = v; bsti[s] = c; }
      }
    }
  // per-row top-2 over 32 entries (LDS scratch overlaps tile buffers)
  __syncthreads();
  float* rv = (float*)smem;            // [128][33]
  int* ri = (int*)(smem + 16896);      // [128][33]
  const int e = (w >> 1) * 16 + l15;   // 0..31
#pragma unroll
  for (int mi = 0; mi < 4; ++mi)
#pragma unroll
    for (int r = 0; r < 4; ++r) {
      const int row = wm + mi * 16 + quad * 4 + r;
      rv[row * 33 + e] = best[mi * 4 + r];
      ri[row * 33 + e] = bsti[mi * 4 + r];
    }
  __syncthreads();
  if (tid < 128) {
    float v1 = 3.4e38f, v2 = 3.4e38f;
    int i1 = 0x7fffffff, i2 = 0x7fffffff;
#pragma unroll
    for (int t = 0; t < 32; ++t) {
      const float v = rv[tid * 33 + t];
      const int i = ri[tid * 33 + t];
      if (v < v1 || (v == v1 && i < i1)) {
        v2 = v1; i2 = i1; v1 = v; i1 = i;
      } else if (v < v2 || (v == v2 && i < i2)) {
        v2 = v; i2 = i;
      }
    }
    const size_t o = ((size_t)blockIdx.y * TT + r0 + tid) * 2;
    bval[o] = v1; bval[o + 1] = v2;
    bidx[o] = i1; bidx[o + 1] = i2;
  }
}

// ---------------- epilogue: butterfly top-2 merge, exact rescore, rotation ----------------
__global__ __launch_bounds__(256) void k_epilogue(
    const float* __restrict__ x, const float* __restrict__ imp,
    const float* __restrict__ cnorm,
    const float* __restrict__ bval, const int* __restrict__ bidx,
    float* __restrict__ outq, float* __restrict__ outidx,
    float* __restrict__ rloss) {
  const int lane = threadIdx.x & 63;
  const int row = blockIdx.x * 4 + (threadIdx.x >> 6);
  // lane p holds split p's sorted top-2; butterfly merge -> global top-2 in all lanes
  const size_t o = ((size_t)lane * TT + row) * 2;
  float v1 = bval[o], v2 = bval[o + 1];
  int i1 = bidx[o], i2 = bidx[o + 1];
#pragma unroll
  for (int m = 1; m < 64; m <<= 1) {
    const float w1 = __shfl_xor(v1, m), w2 = __shfl_xor(v2, m);
    const int j1 = __shfl_xor(i1, m), j2 = __shfl_xor(i2, m);
    if (w1 < v1 || (w1 == v1 && j1 < i1)) {
      if (v1 < w2 || (v1 == w2 && i1 < j2)) { v2 = v1; i2 = i1; }
      else { v2 = w2; i2 = j2; }
      v1 = w1; i1 = j1;
    } else {
      if (w1 < v2 || (w1 == v2 && j1 < i2)) { v2 = w1; i2 = j1; }
    }
  }
  // exact fp32 rescore of both candidates
  const float* xr = x + (size_t)row * DD + lane * 8;
  float e[8], qa[8], qb[8];
  *(float4*)&e[0] = *(const float4*)xr;
  *(float4*)&e[4] = *(const float4*)(xr + 4);
  const float* q1p = imp + (size_t)i1 * DD + lane * 8;
  const float* q2p = imp + (size_t)i2 * DD + lane * 8;
  *(float4*)&qa[0] = *(const float4*)q1p;
  *(float4*)&qa[4] = *(const float4*)(q1p + 4);
  *(float4*)&qb[0] = *(const float4*)q2p;
  *(float4*)&qb[4] = *(const float4*)(q2p + 4);
  float d1 = 0.f, d2 = 0.f;
#pragma unroll
  for (int k = 0; k < 8; ++k) {
    d1 = fmaf(e[k], qa[k], d1);
    d2 = fmaf(e[k], qb[k], d2);
  }
#pragma unroll
  for (int m = 1; m < 64; m <<= 1) {
    d1 += __shfl_xor(d1, m);
    d2 += __shfl_xor(d2, m);
  }
  const float s1 = fmaf(-2.0f, d1, cnorm[i1]);
  const float s2 = fmaf(-2.0f, d2, cnorm[i2]);
  const bool use2 = (s2 < s1) || (s2 == s1 && i2 < i1);
  const int idx = use2 ? i2 : i1;
  float q[8];
#pragma unroll
  for (int k = 0; k < 8; ++k) q[k] = use2 ? qb[k] : qa[k];

  float xx = 0.f, qq = 0.f, xq = 0.f, cl = 0.f;
#pragma unroll
  for (int k = 0; k < 8; ++k) {
    xx = fmaf(e[k], e[k], xx);
    qq = fmaf(q[k], q[k], qq);
    xq = fmaf(e[k], q[k], xq);
    float d = e[k] - q[k] + EPS_PD;
    cl = fmaf(d, d, cl);
  }
#pragma unroll
  for (int m = 1; m < 64; m <<= 1) {
    xx += __shfl_xor(xx, m);
    qq += __shfl_xor(qq, m);
    xq += __shfl_xor(xq, m);
    cl += __shfl_xor(cl, m);
  }
  const float nx = sqrtf(xx), nq = sqrtf(qq);
  const float dx = fmaxf(nx, EPS_DIV), dq = fmaxf(nq, EPS_DIV);
  const float uu = xx / (dx * dx);
  const float qq2 = qq / (dq * dq);
  const float uq = xq / (dx * dq);
  const float ss = uu + qq2 + 2.0f * uq;
  const float dn = fmaxf(sqrtf(ss), EPS_NORM);
  const float es = xx / dx + xq / dq;
  const float a = 2.0f * es / (dn * dn);
  const float b = 2.0f * (xx / dx);
  const float scale = nq / dx;

  float ov[8];
#pragma unroll
  for (int k = 0; k < 8; ++k) {
    const float qp = q[k] / dq;
    const float sk = e[k] / dx + qp;
    ov[k] = (e[k] - a * sk + b * qp) * scale;
  }
  float* op = outq + (size_t)row * DD + lane * 8;
  *(float4*)op = *(const float4*)&ov[0];
  *(float4*)(op + 4) = *(const float4*)&ov[4];
  if (lane == 0) {
    outidx[row] = (float)idx;
    rloss[row] = cl;
  }
}

// ---------------- final loss reduction (deterministic) ----------------
__global__ __launch_bounds__(256) void k_loss_final(
    const float* __restrict__ rloss, float* __restrict__ out) {
  __shared__ double red[256];
  const int tid = threadIdx.x;
  double s = 0.0;
  for (int i = tid; i < TT; i += 256) s += (double)rloss[i];
  red[tid] = s;
  __syncthreads();
  for (int st = 128; st > 0; st >>= 1) {
    if (tid < st) red[tid] += red[tid + st];
    __syncthreads();
  }
  if (tid == 0) out[0] = (float)(red[0] / (double)TT);
}

extern "C" void kernel_launch(void* const* d_in, const int* in_sizes, int n_in,
                              void* d_out, int out_size, void* d_ws, size_t ws_size,
                              hipStream_t stream) {
  const float* x  = (const float*)d_in[0];   // [TT, DD]
  const float* W  = (const float*)d_in[1];   // [DD, DD]
  const float* cb = (const float*)d_in[2];   // [CC, DD]
  float* out = (float*)d_out;

  // workspace layout (~58 MiB); xh aliases cbs (cbs dead after k_gemm_mfma)
  float* imp = (float*)d_ws;                             // CC*DD fp32 (16 MiB)
  _Float16* ih = (_Float16*)(imp + (size_t)CC * DD);     // CC*DD f16 (8 MiB)
  _Float16* cbs = ih + (size_t)CC * DD;                  // CC*1024 f16 (16 MiB)
  _Float16* xh = cbs;                                    // TT*DD f16 (16 MiB, alias)
  _Float16* Ws = cbs + (size_t)CC * 1024;                // DD*1024 f16 (1 MiB)
  float* cnorm = (float*)(Ws + (size_t)DD * 1024);       // CC
  float* bval  = cnorm + CC;                             // SPLITC*TT*2 (8 MiB)
  int*   bidx  = (int*)(bval + (size_t)SPLITC * TT * 2); // 8 MiB
  float* rloss = (float*)(bidx + (size_t)SPLITC * TT * 2);

  float* out_q    = out;
  float* out_idx  = out + (size_t)TT * DD;
  float* out_loss = out_idx + TT;

  k_split<<<CC, 128, 0, stream>>>(cb, cbs);
  k_split<<<DD, 128, 0, stream>>>(W, Ws);
  k_gemm_mfma<<<dim3(CC / 128, DD / 128), 256, 0, stream>>>(cbs, Ws, imp, ih);
  k_row_norm2<<<CC / 4, 256, 0, stream>>>(imp, cnorm);
  k_cast16<<<TT, 128, 0, stream>>>(x, xh);
  k_dist_top2<<<dim3(TT / 128, SPLITC), 256, 0, stream>>>(xh, ih, cnorm, bval, bidx);
  k_epilogue<<<TT / 4, 256, 0, stream>>>(x, imp, cnorm, bval, bidx, out_q, out_idx, rloss);
  k_loss_final<<<1, 256, 0, stream>>>(rloss, out_loss);
}